// Round 5
// baseline (117.970 us; speedup 1.0000x reference)
//
#include <hip/hip_runtime.h>

#define BB 131072
#define DD 512
#define NN 101
#define D4 128               // float4 per row
#define HALF 64              // float4 per half-row
#define NBLK 256             // one block per CU
#define BTHR 1024            // threads per block (16 waves)
#define SPB 1024             // samples per block (131072 / 128 blocks-per-half)
#define NPAIR (NN * NN)      // 10201
#define PPB 80               // gram pairs per block (ceil(10201/128))

typedef float f4 __attribute__((ext_vector_type(4)));

// DIAGNOSTIC ROUND: identical to R4 except the center-sum sweep over emb runs
// TWICE (pass A + bitwise-identical pass B, result averaged -> exactly equal
// to single-pass in fp32). The dur_us delta vs R4 measures the pure marginal
// cost of +268 MB of HBM reads, disambiguating read-BW-ceiling vs overhead.
__global__ __launch_bounds__(BTHR, 1) void fused_kernel(
    const f4* __restrict__ emb, const f4* __restrict__ ctr,
    const int* __restrict__ labels,
    float* __restrict__ partial,   // [NBLK]
    float* __restrict__ G0,        // [NPAIR] half-0 dots
    float* __restrict__ G1)        // [NPAIR] half-1 dots
{
    __shared__ f4  sctr[NN * HALF];   // 103424 B
    __shared__ int slab[SPB];         // 4096 B
    __shared__ float wsum[16];

    int b    = blockIdx.x;
    int h    = b >> 7;               // which feature half
    int blk  = b & 127;              // block index within half
    int tid  = threadIdx.x;
    int wid  = tid >> 6;
    int lane = tid & 63;

    // ---- stage ctr half + labels into LDS ----
    for (int idx = tid; idx < NN * HALF; idx += BTHR) {
        int row = idx >> 6;
        int c   = idx & 63;
        sctr[idx] = ctr[row * D4 + h * HALF + c];
    }
    slab[tid] = labels[blk * SPB + tid];
    __syncthreads();

    // ---- gram half-dots from LDS: 16 waves x 5 reps = 80 pairs ----
    float* Gh = h ? G1 : G0;
#pragma unroll
    for (int rep = 0; rep < 5; rep++) {
        int p = blk * PPB + rep * 16 + wid;
        if (p < NPAIR) {
            int i = p / NN;
            int j = p % NN;
            f4 a = sctr[i * HALF + lane];
            f4 c = sctr[j * HALF + lane];
            float dot = a.x * c.x + a.y * c.y + a.z * c.z + a.w * c.w;
            for (int off = 32; off > 0; off >>= 1)
                dot += __shfl_down(dot, off);
            if (lane == 0) Gh[p] = dot;
        }
    }

    // ---- center (MSE) half-sums: PASS A ----
    float localA = 0.f;
#pragma unroll 1
    for (int kk = 0; kk < 16; kk++) {
        int q0 = (kk * 4 + 0) * 16 + wid;
        int q1 = (kk * 4 + 1) * 16 + wid;
        int q2 = (kk * 4 + 2) * 16 + wid;
        int q3 = (kk * 4 + 3) * 16 + wid;
        int l0 = slab[q0];
        int l1 = slab[q1];
        int l2 = slab[q2];
        int l3 = slab[q3];
        const f4* base = emb + h * HALF + lane;
        f4 e0 = __builtin_nontemporal_load(base + (blk * SPB + q0) * D4);
        f4 e1 = __builtin_nontemporal_load(base + (blk * SPB + q1) * D4);
        f4 e2 = __builtin_nontemporal_load(base + (blk * SPB + q2) * D4);
        f4 e3 = __builtin_nontemporal_load(base + (blk * SPB + q3) * D4);
        f4 c0 = sctr[l0 * HALF + lane];
        f4 c1 = sctr[l1 * HALF + lane];
        f4 c2 = sctr[l2 * HALF + lane];
        f4 c3 = sctr[l3 * HALF + lane];
        f4 t0 = e0 - c0;
        f4 t1 = e1 - c1;
        f4 t2 = e2 - c2;
        f4 t3 = e3 - c3;
        localA += t0.x * t0.x + t0.y * t0.y + t0.z * t0.z + t0.w * t0.w;
        localA += t1.x * t1.x + t1.y * t1.y + t1.z * t1.z + t1.w * t1.w;
        localA += t2.x * t2.x + t2.y * t2.y + t2.z * t2.z + t2.w * t2.w;
        localA += t3.x * t3.x + t3.y * t3.y + t3.z * t3.z + t3.w * t3.w;
    }

    // ---- center (MSE) half-sums: PASS B (bitwise-identical re-read) ----
    float localB = 0.f;
#pragma unroll 1
    for (int kk = 0; kk < 16; kk++) {
        int q0 = (kk * 4 + 0) * 16 + wid;
        int q1 = (kk * 4 + 1) * 16 + wid;
        int q2 = (kk * 4 + 2) * 16 + wid;
        int q3 = (kk * 4 + 3) * 16 + wid;
        int l0 = slab[q0];
        int l1 = slab[q1];
        int l2 = slab[q2];
        int l3 = slab[q3];
        const f4* base = emb + h * HALF + lane;
        f4 e0 = __builtin_nontemporal_load(base + (blk * SPB + q0) * D4);
        f4 e1 = __builtin_nontemporal_load(base + (blk * SPB + q1) * D4);
        f4 e2 = __builtin_nontemporal_load(base + (blk * SPB + q2) * D4);
        f4 e3 = __builtin_nontemporal_load(base + (blk * SPB + q3) * D4);
        f4 c0 = sctr[l0 * HALF + lane];
        f4 c1 = sctr[l1 * HALF + lane];
        f4 c2 = sctr[l2 * HALF + lane];
        f4 c3 = sctr[l3 * HALF + lane];
        f4 t0 = e0 - c0;
        f4 t1 = e1 - c1;
        f4 t2 = e2 - c2;
        f4 t3 = e3 - c3;
        localB += t0.x * t0.x + t0.y * t0.y + t0.z * t0.z + t0.w * t0.w;
        localB += t1.x * t1.x + t1.y * t1.y + t1.z * t1.z + t1.w * t1.w;
        localB += t2.x * t2.x + t2.y * t2.y + t2.z * t2.z + t2.w * t2.w;
        localB += t3.x * t3.x + t3.y * t3.y + t3.z * t3.z + t3.w * t3.w;
    }

    // (A + A) * 0.5 == A bitwise (2x then halve are exact in fp32, no overflow)
    float local = (localA + localB) * 0.5f;

    for (int off = 32; off > 0; off >>= 1)
        local += __shfl_down(local, off);
    if (lane == 0) wsum[wid] = local;
    __syncthreads();
    if (tid == 0) {
        float s = 0.f;
#pragma unroll
        for (int w = 0; w < 16; w++) s += wsum[w];
        partial[b] = s;
    }
}

// ---------------- finalize: UNCHANGED from R4 (one-variable discipline) -------
__global__ __launch_bounds__(256) void finalize_kernel(
    const float* __restrict__ G0, const float* __restrict__ G1,
    const float* __restrict__ partial, float* __restrict__ out)
{
    int t = threadIdx.x;

    double dsum = (t < NBLK) ? (double)partial[t] : 0.0;
    for (int off = 32; off > 0; off >>= 1)
        dsum += __shfl_down(dsum, off);
    __shared__ double dacc[4];
    if ((t & 63) == 0) dacc[t >> 6] = dsum;

    __shared__ float denom[NN];
    __shared__ float mind[NN];
    if (t < NN)
        denom[t] = fmaxf(sqrtf(G0[t * NN + t] + G1[t * NN + t]), 0.1f);
    __syncthreads();
    if (t < NN) {
        float di = denom[t];
        float mn = 1e30f;
        for (int j = 0; j < NN; j++) {
            if (j >= t - 1 && j <= t + 1) continue;
            float g = G0[t * NN + j] + G1[t * NN + j];
            float d = 1.0f - g / (di * denom[j]);
            mn = fminf(mn, d);
        }
        mind[t] = mn;
    }
    __syncthreads();
    float contrib = 0.f;
    if (t >= 1 && t < NN) {
        float g = G0[t * NN + (t - 1)] + G1[t * NN + (t - 1)];
        float dl = 1.0f - g / (denom[t] * denom[t - 1]);
        contrib += fmaxf(2.0f * dl - mind[t], 0.0f);
    }
    if (t < NN - 1) {
        float g = G0[t * NN + (t + 1)] + G1[t * NN + (t + 1)];
        float du = 1.0f - g / (denom[t] * denom[t + 1]);
        contrib += fmaxf(2.0f * du - mind[t], 0.0f);
    }
    for (int off = 32; off > 0; off >>= 1)
        contrib += __shfl_down(contrib, off);
    __shared__ float wsum2[4];
    if ((t & 63) == 0) wsum2[t >> 6] = contrib;
    __syncthreads();
    if (t == 0) {
        float margin = (wsum2[0] + wsum2[1] + wsum2[2] + wsum2[3]) / (float)NN;
        double center = (dacc[0] + dacc[1] + dacc[2] + dacc[3]) / (double)BB;
        out[0] = margin + (float)center;
    }
}

extern "C" void kernel_launch(void* const* d_in, const int* in_sizes, int n_in,
                              void* d_out, int out_size, void* d_ws, size_t ws_size,
                              hipStream_t stream) {
    const float* emb    = (const float*)d_in[0];
    const float* ctr    = (const float*)d_in[1];
    const int*   labels = (const int*)d_in[2];
    float* out = (float*)d_out;

    float* partial = (float*)d_ws;                              // 256 floats
    float* G0      = (float*)((char*)d_ws + 1024);              // NPAIR floats
    float* G1      = G0 + NPAIR;                                // NPAIR floats

    fused_kernel<<<NBLK, BTHR, 0, stream>>>(
        (const f4*)emb, (const f4*)ctr, labels, partial, G0, G1);
    finalize_kernel<<<1, 256, 0, stream>>>(G0, G1, partial, out);
}